// Round 4
// baseline (219.792 us; speedup 1.0000x reference)
//
#include <hip/hip_runtime.h>
#include <hip/hip_bf16.h>

#define B_N 4096
#define S_N 200
#define E_N 32

typedef float f32x4 __attribute__((ext_vector_type(4)));
typedef short s16x8 __attribute__((ext_vector_type(8)));

#define AS1 __attribute__((address_space(1)))
#define AS3 __attribute__((address_space(3)))

static __device__ __forceinline__ float sigmoidf_fast(float x) {
    return __builtin_amdgcn_rcpf(1.0f + __expf(-x));
}

// Stage tile T (16 rows x 128B) of this wave's batch into LDS buffer T%4.
// Lane l sources global (row = T*16 + (l&15), byte col = (l>>4)*32 + j*16);
// HW writes LDS at (uniform base) + l*16 -> identity with the read pattern.
#define STAGE(T) do {                                                          \
    int _row = (T) * 16 + lm;                                                  \
    if (_row > S_N - 1) _row = S_N - 1; /* clamp; masked at consume */         \
    const char* _g = amb + (size_t)_row * 128 + lg * 32;                       \
    char* _l0 = myl + ((T) % 4) * 2048;                                        \
    __builtin_amdgcn_global_load_lds((const AS1 void*)_g, (AS3 void*)_l0,      \
                                     16, 0, 0);                                \
    __builtin_amdgcn_global_load_lds((const AS1 void*)(_g + 16),               \
                                     (AS3 void*)(_l0 + 1024), 16, 0, 0);       \
} while (0)

#define WAITV(N) do {                                                          \
    asm volatile("s_waitcnt vmcnt(" #N ")" ::: "memory");                      \
    __builtin_amdgcn_sched_barrier(0);                                         \
} while (0)

#define TILE(T, WN) do {                                                       \
    if ((T) + 3 < 13) STAGE((T) + 3);                                          \
    WAITV(WN);                                                                 \
    f32x4 v0 = *(const f32x4*)(myl + ((T) % 4) * 2048 + l * 16);               \
    f32x4 v1 = *(const f32x4*)(myl + ((T) % 4) * 2048 + 1024 + l * 16);        \
    if ((T) == 12 && lm >= 8) {  /* rows 200..207 out of range */              \
        v0 = f32x4{0.0f, 0.0f, 0.0f, 0.0f};                                    \
        v1 = f32x4{0.0f, 0.0f, 0.0f, 0.0f};                                    \
    }                                                                          \
    s16x8 af;                                                                  \
    ((__hip_bfloat162*)&af)[0] = __float22bfloat162_rn({v0[0], v0[1]});        \
    ((__hip_bfloat162*)&af)[1] = __float22bfloat162_rn({v0[2], v0[3]});        \
    ((__hip_bfloat162*)&af)[2] = __float22bfloat162_rn({v1[0], v1[1]});        \
    ((__hip_bfloat162*)&af)[3] = __float22bfloat162_rn({v1[2], v1[3]});        \
    f32x4 d0 = __builtin_amdgcn_mfma_f32_16x16x32_bf16(w1A, af, c0, 0, 0, 0);  \
    f32x4 d1 = __builtin_amdgcn_mfma_f32_16x16x32_bf16(w1B, af, c1, 0, 0, 0);  \
    float s = 0.0f;                                                            \
    _Pragma("unroll")                                                          \
    for (int j = 0; j < 4; ++j) {                                              \
        s += w4A[j] * sigmoidf_fast(d0[j]);                                    \
        s += w4B[j] * sigmoidf_fast(d1[j]);                                    \
    }                                                                          \
    s += __shfl_xor(s, 16);                                                    \
    s += __shfl_xor(s, 32);                                                    \
    _Pragma("unroll")                                                          \
    for (int i = 0; i < 4; ++i) {                                              \
        acc[i]     += s * v0[i];                                               \
        acc[4 + i] += s * v1[i];                                               \
    }                                                                          \
} while (0)

__global__ __launch_bounds__(256, 4) void attn_pool_kernel(
    const float* __restrict__ am,    // [B,S,E]
    const float* __restrict__ lastm, // [B,E]
    const float* __restrict__ avgm,  // [B,E]
    const float* __restrict__ W1,    // [E,E]
    const float* __restrict__ b1,    // [E]
    const float* __restrict__ W2,    // [E,E]
    const float* __restrict__ b2,    // [E]
    const float* __restrict__ W3,    // [E,E]
    const float* __restrict__ b3,    // [E]
    const float* __restrict__ W4,    // [E,1]
    float* __restrict__ out)         // [B,E]
{
    __shared__ char lds[4][4][2048];   // [wave][buf][2KB tile] — per-wave private

    const int tid  = threadIdx.x;
    const int l    = tid & 63;
    const int wave = tid >> 6;
    const int b    = blockIdx.x * 4 + wave;

    const int lm = l & 15;   // A-frag row f (mod 16) / am row-slot r
    const int lg = l >> 4;   // k-slice group
    const int fi = l & 31;
    const int e0 = 8 * lg;

    // ---- weight A-fragments: A[m=f][k=e] = W[e*32+f], lane: m=lm(+16), k=e0+i ----
    s16x8 w1A, w1B, w2A, w2B, w3A, w3B;
#pragma unroll
    for (int i = 0; i < 8; i += 2) {
        int e = e0 + i;
        float2 p;
        p = {W1[e * E_N + lm],      W1[(e + 1) * E_N + lm]};
        ((__hip_bfloat162*)&w1A)[i >> 1] = __float22bfloat162_rn(p);
        p = {W1[e * E_N + 16 + lm], W1[(e + 1) * E_N + 16 + lm]};
        ((__hip_bfloat162*)&w1B)[i >> 1] = __float22bfloat162_rn(p);
        p = {W2[e * E_N + lm],      W2[(e + 1) * E_N + lm]};
        ((__hip_bfloat162*)&w2A)[i >> 1] = __float22bfloat162_rn(p);
        p = {W2[e * E_N + 16 + lm], W2[(e + 1) * E_N + 16 + lm]};
        ((__hip_bfloat162*)&w2B)[i >> 1] = __float22bfloat162_rn(p);
        p = {W3[e * E_N + lm],      W3[(e + 1) * E_N + lm]};
        ((__hip_bfloat162*)&w3A)[i >> 1] = __float22bfloat162_rn(p);
        p = {W3[e * E_N + 16 + lm], W3[(e + 1) * E_N + 16 + lm]};
        ((__hip_bfloat162*)&w3B)[i >> 1] = __float22bfloat162_rn(p);
    }

    // ---- last/avg as broadcast-column B-frags: B[k][n] = v[k] for all n ----
    s16x8 lfrag, vfrag;
    {
        const f32x4* pl = (const f32x4*)(lastm + (size_t)b * E_N + e0);
        const f32x4* pa = (const f32x4*)(avgm  + (size_t)b * E_N + e0);
        f32x4 l0 = pl[0], l1 = pl[1];
        f32x4 a0 = pa[0], a1 = pa[1];
#pragma unroll
        for (int i = 0; i < 4; i += 2) {
            ((__hip_bfloat162*)&lfrag)[i >> 1]       = __float22bfloat162_rn({l0[i], l0[i + 1]});
            ((__hip_bfloat162*)&lfrag)[(i + 4) >> 1] = __float22bfloat162_rn({l1[i], l1[i + 1]});
            ((__hip_bfloat162*)&vfrag)[i >> 1]       = __float22bfloat162_rn({a0[i], a0[i + 1]});
            ((__hip_bfloat162*)&vfrag)[(i + 4) >> 1] = __float22bfloat162_rn({a1[i], a1[i + 1]});
        }
    }

    // ---- bias C-input + fold last@W2 + avg@W3 (broadcast over all 16 cols) ----
    float bsum = b1[fi] + b2[fi] + b3[fi];
    f32x4 c0, c1, w4A, w4B;
#pragma unroll
    for (int j = 0; j < 4; ++j) {
        c0[j]  = __shfl(bsum, 4 * lg + j);
        c1[j]  = __shfl(bsum, 16 + 4 * lg + j);
        w4A[j] = W4[4 * lg + j];
        w4B[j] = W4[16 + 4 * lg + j];
    }
    c0 = __builtin_amdgcn_mfma_f32_16x16x32_bf16(w2A, lfrag, c0, 0, 0, 0);
    c0 = __builtin_amdgcn_mfma_f32_16x16x32_bf16(w3A, vfrag, c0, 0, 0, 0);
    c1 = __builtin_amdgcn_mfma_f32_16x16x32_bf16(w2B, lfrag, c1, 0, 0, 0);
    c1 = __builtin_amdgcn_mfma_f32_16x16x32_bf16(w3B, vfrag, c1, 0, 0, 0);

    const char* amb = (const char*)(am + (size_t)b * S_N * E_N);
    char* myl = &lds[wave][0][0];

    // ---- prime the async pipeline: tiles 0..2 (6 loads in flight) ----
    STAGE(0); STAGE(1); STAGE(2);

    float acc[8];
#pragma unroll
    for (int i = 0; i < 8; ++i) acc[i] = 0.0f;

    // Steady state: issue tile t+3, wait vmcnt(6) -> tile t resident, compute.
    TILE(0, 6);  TILE(1, 6);  TILE(2, 6);  TILE(3, 6);  TILE(4, 6);
    TILE(5, 6);  TILE(6, 6);  TILE(7, 6);  TILE(8, 6);  TILE(9, 6);
    TILE(10, 4); TILE(11, 2); TILE(12, 0);

    // reduce over the 16 row-slots within each e-slice group
#pragma unroll
    for (int i = 0; i < 8; ++i) {
        acc[i] += __shfl_xor(acc[i], 1);
        acc[i] += __shfl_xor(acc[i], 2);
        acc[i] += __shfl_xor(acc[i], 4);
        acc[i] += __shfl_xor(acc[i], 8);
    }
    if (lm == 0) {
        f32x4 o0, o1;
#pragma unroll
        for (int i = 0; i < 4; ++i) { o0[i] = acc[i]; o1[i] = acc[4 + i]; }
        f32x4* po = (f32x4*)(out + (size_t)b * E_N + e0);
        po[0] = o0;
        po[1] = o1;
    }
}

extern "C" void kernel_launch(void* const* d_in, const int* in_sizes, int n_in,
                              void* d_out, int out_size, void* d_ws, size_t ws_size,
                              hipStream_t stream) {
    const float* am    = (const float*)d_in[0];
    const float* lastm = (const float*)d_in[1];
    const float* avgm  = (const float*)d_in[2];
    // d_in[3] = mask: dead code in the reference
    const float* W1 = (const float*)d_in[4];
    const float* b1 = (const float*)d_in[5];
    const float* W2 = (const float*)d_in[6];
    const float* b2 = (const float*)d_in[7];
    const float* W3 = (const float*)d_in[8];
    const float* b3 = (const float*)d_in[9];
    const float* W4 = (const float*)d_in[10];
    float* out = (float*)d_out;

    dim3 grid(B_N / 4);
    dim3 block(256);
    hipLaunchKernelGGL(attn_pool_kernel, grid, block, 0, stream,
                       am, lastm, avgm, W1, b1, W2, b2, W3, b3, W4, out);
}

// Round 5
// 177.446 us; speedup vs baseline: 1.2386x; 1.2386x over previous
//
#include <hip/hip_runtime.h>
#include <hip/hip_bf16.h>

#define B_N 4096
#define S_N 200
#define E_N 32

typedef float f32x4 __attribute__((ext_vector_type(4)));
typedef short s16x8 __attribute__((ext_vector_type(8)));

static __device__ __forceinline__ float sigmoidf_fast(float x) {
    return __builtin_amdgcn_rcpf(1.0f + __expf(-x));
}

// 2 batches per block, 2 waves per batch (S split 112/88). 32 waves/CU.
__global__ __launch_bounds__(256, 8) void attn_pool_kernel(
    const float* __restrict__ am,    // [B,S,E]
    const float* __restrict__ lastm, // [B,E]
    const float* __restrict__ avgm,  // [B,E]
    const float* __restrict__ W1,    // [E,E]
    const float* __restrict__ b1,    // [E]
    const float* __restrict__ W2,    // [E,E]
    const float* __restrict__ b2,    // [E]
    const float* __restrict__ W3,    // [E,E]
    const float* __restrict__ b3,    // [E]
    const float* __restrict__ W4,    // [E,1]
    float* __restrict__ out)         // [B,E]
{
    __shared__ float red[2][2][32];  // [batch-slot][half][e]

    const int tid  = threadIdx.x;
    const int l    = tid & 63;
    const int wave = tid >> 6;       // 0..3
    const int bs   = wave >> 1;      // batch slot within block
    const int h    = wave & 1;       // S-half: 0 -> rows 0..111, 1 -> rows 112..199
    const int b    = blockIdx.x * 2 + bs;

    const int lm = l & 15;   // A-frag row f (mod 16) / am row-slot r
    const int lg = l >> 4;   // k-slice group
    const int fi = l & 31;
    const int e0 = 8 * lg;

    // ---- weight A-fragments: A[m=f][k=e] = W[e*32+f], lane: m=lm(+16), k=e0+i ----
    s16x8 w1A, w1B;
    f32x4 c0, c1, w4A, w4B;
    {
        s16x8 w2A, w2B, w3A, w3B;
#pragma unroll
        for (int i = 0; i < 8; i += 2) {
            int e = e0 + i;
            float2 p;
            p = {W1[e * E_N + lm],      W1[(e + 1) * E_N + lm]};
            ((__hip_bfloat162*)&w1A)[i >> 1] = __float22bfloat162_rn(p);
            p = {W1[e * E_N + 16 + lm], W1[(e + 1) * E_N + 16 + lm]};
            ((__hip_bfloat162*)&w1B)[i >> 1] = __float22bfloat162_rn(p);
            p = {W2[e * E_N + lm],      W2[(e + 1) * E_N + lm]};
            ((__hip_bfloat162*)&w2A)[i >> 1] = __float22bfloat162_rn(p);
            p = {W2[e * E_N + 16 + lm], W2[(e + 1) * E_N + 16 + lm]};
            ((__hip_bfloat162*)&w2B)[i >> 1] = __float22bfloat162_rn(p);
            p = {W3[e * E_N + lm],      W3[(e + 1) * E_N + lm]};
            ((__hip_bfloat162*)&w3A)[i >> 1] = __float22bfloat162_rn(p);
            p = {W3[e * E_N + 16 + lm], W3[(e + 1) * E_N + 16 + lm]};
            ((__hip_bfloat162*)&w3B)[i >> 1] = __float22bfloat162_rn(p);
        }

        // last/avg as broadcast-column B-frags: B[k][n] = v[k] for all n
        s16x8 lfrag, vfrag;
        {
            const f32x4* pl = (const f32x4*)(lastm + (size_t)b * E_N + e0);
            const f32x4* pa = (const f32x4*)(avgm  + (size_t)b * E_N + e0);
            f32x4 l0 = pl[0], l1 = pl[1];
            f32x4 a0 = pa[0], a1 = pa[1];
#pragma unroll
            for (int i = 0; i < 4; i += 2) {
                ((__hip_bfloat162*)&lfrag)[i >> 1]       = __float22bfloat162_rn({l0[i], l0[i + 1]});
                ((__hip_bfloat162*)&lfrag)[(i + 4) >> 1] = __float22bfloat162_rn({l1[i], l1[i + 1]});
                ((__hip_bfloat162*)&vfrag)[i >> 1]       = __float22bfloat162_rn({a0[i], a0[i + 1]});
                ((__hip_bfloat162*)&vfrag)[(i + 4) >> 1] = __float22bfloat162_rn({a1[i], a1[i + 1]});
            }
        }

        // bias C-input + fold last@W2 + avg@W3 (broadcast over all 16 cols)
        float bsum = b1[fi] + b2[fi] + b3[fi];
#pragma unroll
        for (int j = 0; j < 4; ++j) {
            c0[j]  = __shfl(bsum, 4 * lg + j);
            c1[j]  = __shfl(bsum, 16 + 4 * lg + j);
            w4A[j] = W4[4 * lg + j];
            w4B[j] = W4[16 + 4 * lg + j];
        }
        c0 = __builtin_amdgcn_mfma_f32_16x16x32_bf16(w2A, lfrag, c0, 0, 0, 0);
        c0 = __builtin_amdgcn_mfma_f32_16x16x32_bf16(w3A, vfrag, c0, 0, 0, 0);
        c1 = __builtin_amdgcn_mfma_f32_16x16x32_bf16(w2B, lfrag, c1, 0, 0, 0);
        c1 = __builtin_amdgcn_mfma_f32_16x16x32_bf16(w3B, vfrag, c1, 0, 0, 0);
    }

    const int row0 = h * 112;        // h0: 7 tiles (rows 0..111), h1: 6 tiles (112..199)
    const int nt   = 7 - h;
    const float* rowbase = am + ((size_t)b * S_N + row0) * E_N + e0;

    float acc[8];
#pragma unroll
    for (int i = 0; i < 8; ++i) acc[i] = 0.0f;

    float amf[8], nxt[8];
    {   // tile 0 always fully valid for both halves
        const f32x4* p = (const f32x4*)(rowbase + (size_t)lm * E_N);
        f32x4 v0 = p[0], v1 = p[1];
#pragma unroll
        for (int i = 0; i < 4; ++i) { amf[i] = v0[i]; amf[4 + i] = v1[i]; }
    }

    for (int t = 0; t < nt; ++t) {
        // depth-1 prefetch of tile t+1 (row clamped; masked at consume)
        if (t + 1 < nt) {
            int r = (t + 1) * 16 + lm;
            if (row0 + r > S_N - 1) r = S_N - 1 - row0;
            const f32x4* p = (const f32x4*)(rowbase + (size_t)r * E_N);
            f32x4 v0 = p[0], v1 = p[1];
#pragma unroll
            for (int i = 0; i < 4; ++i) { nxt[i] = v0[i]; nxt[4 + i] = v1[i]; }
        }

        float v0[4], v1[4];
        const bool dead = (h == 1) && (t == 5) && (lm >= 8);  // rows 200..207
#pragma unroll
        for (int i = 0; i < 4; ++i) {
            v0[i] = dead ? 0.0f : amf[i];
            v1[i] = dead ? 0.0f : amf[4 + i];
        }

        // am rows as B-operand: B[k=e][n=r], lane col=lm, k=e0+i
        s16x8 af;
        ((__hip_bfloat162*)&af)[0] = __float22bfloat162_rn({v0[0], v0[1]});
        ((__hip_bfloat162*)&af)[1] = __float22bfloat162_rn({v0[2], v0[3]});
        ((__hip_bfloat162*)&af)[2] = __float22bfloat162_rn({v1[0], v1[1]});
        ((__hip_bfloat162*)&af)[3] = __float22bfloat162_rn({v1[2], v1[3]});

        // D[f][r] = (W1^T am^T)[f][r] + base[f]
        f32x4 d0 = __builtin_amdgcn_mfma_f32_16x16x32_bf16(w1A, af, c0, 0, 0, 0);
        f32x4 d1 = __builtin_amdgcn_mfma_f32_16x16x32_bf16(w1B, af, c1, 0, 0, 0);

        float s = 0.0f;
#pragma unroll
        for (int j = 0; j < 4; ++j) {
            s += w4A[j] * sigmoidf_fast(d0[j]);
            s += w4B[j] * sigmoidf_fast(d1[j]);
        }
        s += __shfl_xor(s, 16);
        s += __shfl_xor(s, 32);
        // s = score for this lane's own row r = row0 + t*16 + lm

#pragma unroll
        for (int i = 0; i < 4; ++i) {
            acc[i]     += s * v0[i];
            acc[4 + i] += s * v1[i];
        }
#pragma unroll
        for (int i = 0; i < 8; ++i) amf[i] = nxt[i];
    }

    // reduce over the 16 row-slots within each e-slice group
#pragma unroll
    for (int i = 0; i < 8; ++i) {
        acc[i] += __shfl_xor(acc[i], 1);
        acc[i] += __shfl_xor(acc[i], 2);
        acc[i] += __shfl_xor(acc[i], 4);
        acc[i] += __shfl_xor(acc[i], 8);
    }

    // combine the two S-halves through LDS
    if (lm == 0) {
        f32x4 o0, o1;
#pragma unroll
        for (int i = 0; i < 4; ++i) { o0[i] = acc[i]; o1[i] = acc[4 + i]; }
        *(f32x4*)&red[bs][h][e0]     = o0;
        *(f32x4*)&red[bs][h][e0 + 4] = o1;
    }
    __syncthreads();
    if (h == 0 && lm == 0) {
        f32x4 p0 = *(const f32x4*)&red[bs][1][e0];
        f32x4 p1 = *(const f32x4*)&red[bs][1][e0 + 4];
        f32x4 o0, o1;
#pragma unroll
        for (int i = 0; i < 4; ++i) { o0[i] = acc[i] + p0[i]; o1[i] = acc[4 + i] + p1[i]; }
        f32x4* po = (f32x4*)(out + (size_t)b * E_N + e0);
        po[0] = o0;
        po[1] = o1;
    }
}

extern "C" void kernel_launch(void* const* d_in, const int* in_sizes, int n_in,
                              void* d_out, int out_size, void* d_ws, size_t ws_size,
                              hipStream_t stream) {
    const float* am    = (const float*)d_in[0];
    const float* lastm = (const float*)d_in[1];
    const float* avgm  = (const float*)d_in[2];
    // d_in[3] = mask: dead code in the reference
    const float* W1 = (const float*)d_in[4];
    const float* b1 = (const float*)d_in[5];
    const float* W2 = (const float*)d_in[6];
    const float* b2 = (const float*)d_in[7];
    const float* W3 = (const float*)d_in[8];
    const float* b3 = (const float*)d_in[9];
    const float* W4 = (const float*)d_in[10];
    float* out = (float*)d_out;

    dim3 grid(B_N / 2);   // 2 batches per block, 2 waves per batch
    dim3 block(256);
    hipLaunchKernelGGL(attn_pool_kernel, grid, block, 0, stream,
                       am, lastm, avgm, W1, b1, W2, b2, W3, b3, W4, out);
}